// Round 7
// baseline (374.289 us; speedup 1.0000x reference)
//
#include <hip/hip_runtime.h>
#include <hip/hip_bf16.h>

#define NROWS 50000
#define MOBS  2048
#define EDIM  512
#define ODIM  256
#define RT    32                 // rows per tile
#define NT    1563               // ceil(NROWS/RT)
#define GRID_MAIN 512

typedef short s16x8 __attribute__((ext_vector_type(8)));
typedef float f32x4 __attribute__((ext_vector_type(4)));

__device__ __forceinline__ unsigned short f32_to_bf16(float f) {
    unsigned int u = __float_as_uint(f);
    u += 0x7fffu + ((u >> 16) & 1u);     // RNE
    return (unsigned short)(u >> 16);
}

__device__ __forceinline__ unsigned int cvt_pk(float lo, float hi) {
    unsigned int r;
    asm("v_cvt_pk_bf16_f32 %0, %1, %2" : "=v"(r) : "v"(lo), "v"(hi));
    return r;
}

// ---------------------------------------------------------------------------
// D1: G = obs^T obs (b<256, split-K 16) and P = Wq^T Wk (b>=256, split-K 4).
// 64x64 tiles, atomicAdd into pre-zeroed C.
// ---------------------------------------------------------------------------
__global__ __launch_bounds__(256) void gp_fused(const float* __restrict__ obs,
                                                const float* __restrict__ Wq,
                                                const float* __restrict__ Wk,
                                                float* __restrict__ G,
                                                float* __restrict__ P) {
    __shared__ float SA[16][68];
    __shared__ float SB[16][68];
    const int b = blockIdx.x;
    const float *A, *B;
    float* C;
    int lda, ldb, k_lo, k_hi, bx, by;
    if (b < 256) {
        bx = b & 3; by = (b >> 2) & 3; int bz = b >> 4;
        A = obs; B = obs; C = G; lda = ODIM; ldb = ODIM;
        k_lo = bz * (MOBS / 16); k_hi = k_lo + MOBS / 16;
    } else {
        int i = b - 256;
        bx = i & 3; by = (i >> 2) & 7; int bz = i >> 5;
        A = Wq; B = Wk; C = P; lda = EDIM; ldb = ODIM;
        k_lo = bz * (EDIM / 4); k_hi = k_lo + EDIM / 4;
    }
    const int t  = threadIdx.x;
    const int tx = t & 15, ty = t >> 4;
    const int i0 = by * 64, j0 = bx * 64;

    float acc[4][4];
#pragma unroll
    for (int a = 0; a < 4; ++a)
#pragma unroll
        for (int c2 = 0; c2 < 4; ++c2) acc[a][c2] = 0.f;

    for (int k0 = k_lo; k0 < k_hi; k0 += 16) {
#pragma unroll
        for (int r = 0; r < 4; ++r) {
            int idx = t + 256 * r;
            int mm = idx & 63, kk2 = idx >> 6;
            SA[kk2][mm] = A[(size_t)(k0 + kk2) * lda + i0 + mm];
        }
#pragma unroll
        for (int r = 0; r < 4; ++r) {
            int idx = t + 256 * r;
            int jj = idx & 63, kk2 = idx >> 6;
            SB[kk2][jj] = B[(size_t)(k0 + kk2) * ldb + j0 + jj];
        }
        __syncthreads();
#pragma unroll
        for (int kk2 = 0; kk2 < 16; ++kk2) {
            float4 a4 = *(const float4*)&SA[kk2][ty * 4];
            float4 b4 = *(const float4*)&SB[kk2][tx * 4];
            float av[4] = {a4.x, a4.y, a4.z, a4.w};
            float bv[4] = {b4.x, b4.y, b4.z, b4.w};
#pragma unroll
            for (int a = 0; a < 4; ++a)
#pragma unroll
                for (int c2 = 0; c2 < 4; ++c2) acc[a][c2] += av[a] * bv[c2];
        }
        __syncthreads();
    }
#pragma unroll
    for (int a = 0; a < 4; ++a)
#pragma unroll
        for (int c2 = 0; c2 < 4; ++c2)
            atomicAdd(&C[(size_t)(i0 + ty * 4 + a) * ODIM + j0 + tx * 4 + c2],
                      acc[a][c2]);
}

// ---------------------------------------------------------------------------
// Small-chain GEMM: 64x64 tile, 4x4 micro-tile, split-K / frag-major output.
// ---------------------------------------------------------------------------
template <int TA, int TB, int SPLIT, int FRAG>
__global__ __launch_bounds__(256) void sgemm4(const float* __restrict__ A,
                                              const float* __restrict__ B,
                                              void* __restrict__ Cv,
                                              int NN, int KK, int lda, int ldb) {
    __shared__ float SA[16][68];
    __shared__ float SB[16][68];
    const int t  = threadIdx.x;
    const int tx = t & 15, ty = t >> 4;
    const int i0 = blockIdx.y * 64, j0 = blockIdx.x * 64;
    int k_lo = 0, k_hi = KK;
    if (SPLIT > 1) { int ch = KK / SPLIT; k_lo = blockIdx.z * ch; k_hi = k_lo + ch; }

    float acc[4][4];
#pragma unroll
    for (int a = 0; a < 4; ++a)
#pragma unroll
        for (int b = 0; b < 4; ++b) acc[a][b] = 0.f;

    for (int k0 = k_lo; k0 < k_hi; k0 += 16) {
#pragma unroll
        for (int r = 0; r < 4; ++r) {
            int idx = t + 256 * r;
            int mm, kk2;
            if (TA) { mm = idx & 63; kk2 = idx >> 6; }
            else    { kk2 = idx & 15; mm = idx >> 4; }
            SA[kk2][mm] = TA ? A[(size_t)(k0 + kk2) * lda + i0 + mm]
                             : A[(size_t)(i0 + mm) * lda + k0 + kk2];
        }
#pragma unroll
        for (int r = 0; r < 4; ++r) {
            int idx = t + 256 * r;
            int jj, kk2;
            if (TB) { kk2 = idx & 15; jj = idx >> 4; }
            else    { jj = idx & 63; kk2 = idx >> 6; }
            SB[kk2][jj] = TB ? B[(size_t)(j0 + jj) * ldb + k0 + kk2]
                             : B[(size_t)(k0 + kk2) * ldb + j0 + jj];
        }
        __syncthreads();
#pragma unroll
        for (int kk2 = 0; kk2 < 16; ++kk2) {
            float4 a4 = *(const float4*)&SA[kk2][ty * 4];
            float4 b4 = *(const float4*)&SB[kk2][tx * 4];
            float av[4] = {a4.x, a4.y, a4.z, a4.w};
            float bv[4] = {b4.x, b4.y, b4.z, b4.w};
#pragma unroll
            for (int a = 0; a < 4; ++a)
#pragma unroll
                for (int b = 0; b < 4; ++b) acc[a][b] += av[a] * bv[b];
        }
        __syncthreads();
    }

    if (FRAG) {
        unsigned short* C = (unsigned short*)Cv;
#pragma unroll
        for (int a = 0; a < 4; ++a)
#pragma unroll
            for (int b = 0; b < 4; ++b) {
                int i = i0 + ty * 4 + a;       // k-dim of main GEMM
                int j = j0 + tx * 4 + b;       // col of main GEMM
                float v = acc[a][b] + (i == j ? 1.f : 0.f);
                int f = j >> 4, lr = j & 15, kk = i >> 5, lk = (i >> 3) & 3;
                C[((size_t)((f * 16 + kk) * 64 + lk * 16 + lr)) * 8 + (i & 7)] =
                    f32_to_bf16(v);
            }
    } else if (SPLIT > 1) {
        float* C = (float*)Cv;
#pragma unroll
        for (int a = 0; a < 4; ++a)
#pragma unroll
            for (int b = 0; b < 4; ++b)
                atomicAdd(&C[(size_t)(i0 + ty * 4 + a) * NN + j0 + tx * 4 + b],
                          acc[a][b]);
    } else {
        float* C = (float*)Cv;
#pragma unroll
        for (int a = 0; a < 4; ++a) {
            float4 o = make_float4(acc[a][0], acc[a][1], acc[a][2], acc[a][3]);
            *(float4*)&C[(size_t)(i0 + ty * 4 + a) * NN + j0 + tx * 4] = o;
        }
    }
}

// ---------------------------------------------------------------------------
// Main: out = LayerNorm(node @ (U+I)), persistent blocks, 32-row tiles.
// Block 512 thr = 8 waves; wave w: cols [w*64, w*64+64), rows all 32
// (mi=2, ni=4, acc=32 VGPR). B-traffic dup-free (Uf once per tile).
// Tile loop: issue global loads of tile t+1 into regs BEFORE computing
// tile t from LDS (dbuf); cvt_pk + ds_write after epilogue. Barrier-free
// kk-loop; 3 barriers per tile.
// ---------------------------------------------------------------------------
__global__ __launch_bounds__(512, 4) void gemm_tile_ln(
    const float* __restrict__ node, const unsigned short* __restrict__ Uf,
    const float* __restrict__ gamma, const float* __restrict__ beta,
    float* __restrict__ out) {
    __shared__ unsigned short Ab[2][RT * EDIM];   // 2 x 32 KB
    __shared__ float lds_s[8][RT];
    __shared__ float lds_q[8][RT];
    __shared__ float lds_mu[RT];
    __shared__ float lds_rs[RT];

    const int t  = threadIdx.x;
    const int w  = t >> 6, l = t & 63;
    const int lr = l & 15, lk = l >> 4;
    // stage mapping: thread t covers row (t>>4), float cols (t&15)*4 + k*64
    const int srow = t >> 4, sch = t & 15;

    // B base: wave w owns col-frags f = w*4+ni; frag (f,kk) at (f*16+kk)*512
    const unsigned short* ubase = Uf + (size_t)w * 32768 + (size_t)l * 8;

    float gv[4], bv[4];
#pragma unroll
    for (int ni = 0; ni < 4; ++ni) {
        int col = w * 64 + ni * 16 + lr;
        gv[ni] = gamma[col];
        bv[ni] = beta[col];
    }

    float4 st[8];
    // ---- prologue: load + stage tile blockIdx.x into buf 0 ----
    {
        int gr = blockIdx.x * RT + srow;
        if (gr > NROWS - 1) gr = NROWS - 1;
        const float4* sp = (const float4*)(node + (size_t)gr * EDIM + sch * 4);
#pragma unroll
        for (int k = 0; k < 8; ++k) st[k] = sp[k * 16];
        char* base = (char*)&Ab[0][0] + srow * 1024;
#pragma unroll
        for (int k = 0; k < 8; ++k) {
            unsigned int p0 = cvt_pk(st[k].x, st[k].y);
            unsigned int p1 = cvt_pk(st[k].z, st[k].w);
            int byte = (sch * 8 + k * 128) ^ ((srow & 7) << 4);
            uint2 v; v.x = p0; v.y = p1;
            *(uint2*)(base + byte) = v;
        }
    }
    __syncthreads();

    int cur = 0;
#pragma unroll 1
    for (int tile = blockIdx.x; tile < NT; tile += GRID_MAIN) {
        const int tnext = tile + GRID_MAIN;
        const bool pf = tnext < NT;
        // ---- issue next tile's loads (latency hides under compute) ----
        if (pf) {
            int gr = tnext * RT + srow;
            if (gr > NROWS - 1) gr = NROWS - 1;
            const float4* sp = (const float4*)(node + (size_t)gr * EDIM + sch * 4);
#pragma unroll
            for (int k = 0; k < 8; ++k) st[k] = sp[k * 16];
        }

        // ---- compute tile from Ab[cur]: barrier-free kk loop ----
        f32x4 acc[2][4];
#pragma unroll
        for (int mi = 0; mi < 2; ++mi)
#pragma unroll
            for (int ni = 0; ni < 4; ++ni)
                acc[mi][ni] = (f32x4){0.f, 0.f, 0.f, 0.f};

        const char* ab = (const char*)&Ab[cur][0];
#pragma unroll
        for (int kk = 0; kk < 16; ++kk) {
            s16x8 bfr[4], afr[2];
#pragma unroll
            for (int ni = 0; ni < 4; ++ni)
                bfr[ni] = *(const s16x8*)(ubase + (size_t)ni * 8192 + kk * 512);
#pragma unroll
            for (int mi = 0; mi < 2; ++mi) {
                int row = mi * 16 + lr;
                int byte = row * 1024 + ((kk * 64 + lk * 16) ^ ((lr & 7) << 4));
                afr[mi] = *(const s16x8*)(ab + byte);
            }
#pragma unroll
            for (int mi = 0; mi < 2; ++mi)
#pragma unroll
                for (int ni = 0; ni < 4; ++ni)
                    acc[mi][ni] = __builtin_amdgcn_mfma_f32_16x16x32_bf16(
                        afr[mi], bfr[ni], acc[mi][ni], 0, 0, 0);
        }

        // ---- LN stats ----
#pragma unroll
        for (int mi = 0; mi < 2; ++mi) {
#pragma unroll
            for (int j = 0; j < 4; ++j) {
                float sm = 0.f, q = 0.f;
#pragma unroll
                for (int ni = 0; ni < 4; ++ni) {
                    float v = acc[mi][ni][j];
                    sm += v; q += v * v;
                }
#pragma unroll
                for (int off = 1; off < 16; off <<= 1) {
                    sm += __shfl_xor(sm, off);
                    q  += __shfl_xor(q, off);
                }
                if (lr == 0) {
                    int rl = mi * 16 + lk * 4 + j;
                    lds_s[w][rl] = sm;
                    lds_q[w][rl] = q;
                }
            }
        }
        __syncthreads();
        if (t < RT) {
            float sm = 0.f, q = 0.f;
#pragma unroll
            for (int ww = 0; ww < 8; ++ww) {
                sm += lds_s[ww][t];
                q  += lds_q[ww][t];
            }
            float mu  = sm * (1.f / (float)EDIM);
            float var = q * (1.f / (float)EDIM) - mu * mu;
            lds_mu[t] = mu;
            lds_rs[t] = rsqrtf(var + 1e-6f);
        }
        __syncthreads();

        // ---- epilogue stores ----
#pragma unroll
        for (int mi = 0; mi < 2; ++mi) {
#pragma unroll
            for (int j = 0; j < 4; ++j) {
                int rl = mi * 16 + lk * 4 + j;
                int gr = tile * RT + rl;
                if (gr < NROWS) {
                    float mu = lds_mu[rl], rs = lds_rs[rl];
                    float* op = out + (size_t)gr * EDIM + w * 64 + lr;
#pragma unroll
                    for (int ni = 0; ni < 4; ++ni)
                        op[ni * 16] = (acc[mi][ni][j] - mu) * rs * gv[ni] + bv[ni];
                }
            }
        }

        // ---- stage next tile into other buffer ----
        if (pf) {
            char* base = (char*)&Ab[cur ^ 1][0] + srow * 1024;
#pragma unroll
            for (int k = 0; k < 8; ++k) {
                unsigned int p0 = cvt_pk(st[k].x, st[k].y);
                unsigned int p1 = cvt_pk(st[k].z, st[k].w);
                int byte = (sch * 8 + k * 128) ^ ((srow & 7) << 4);
                uint2 v; v.x = p0; v.y = p1;
                *(uint2*)(base + byte) = v;
            }
        }
        __syncthreads();
        cur ^= 1;
    }
}

// ---------------------------------------------------------------------------
extern "C" void kernel_launch(void* const* d_in, const int* in_sizes, int n_in,
                              void* d_out, int out_size, void* d_ws, size_t ws_size,
                              hipStream_t stream) {
    const float* node  = (const float*)d_in[0];   // [N, E]
    const float* obs   = (const float*)d_in[1];   // [M, O]
    const float* Wq    = (const float*)d_in[2];   // [E, E]
    const float* Wk    = (const float*)d_in[3];   // [E, O]
    const float* Wv    = (const float*)d_in[4];   // [E, O]
    const float* gamma = (const float*)d_in[5];   // [E]
    const float* beta  = (const float*)d_in[6];   // [E]
    float* out = (float*)d_out;

    float* ws = (float*)d_ws;
    float*          G  = ws;                        // [256,256] f32
    float*          P  = G  + ODIM * ODIM;          // [512,256] f32  (Wq^T Wk)
    float*          GV = P  + EDIM * ODIM;          // [256,512] f32  (G Wv^T)
    unsigned short* Uf = (unsigned short*)(GV + ODIM * EDIM); // frag bf16

    // zero split-K accumulators G, P, GV
    hipMemsetAsync((void*)G, 0,
                   (ODIM * ODIM + 2 * EDIM * ODIM) * sizeof(float), stream);

    // D1: G = obs^T obs (split-K 16) + P = Wq^T Wk (split-K 4)
    gp_fused<<<dim3(384), 256, 0, stream>>>(obs, Wq, Wk, G, P);
    // D2: GV = G @ Wv^T        [256,512] K=256, split-K 4
    sgemm4<0, 1, 4, 0><<<dim3(8, 4, 4), 256, 0, stream>>>(G, Wv, GV, EDIM, ODIM, ODIM, ODIM);
    // D3: Uf = frag(P @ GV + I) [512,512] K=256
    sgemm4<0, 0, 1, 1><<<dim3(8, 8, 1), 256, 0, stream>>>(P, GV, Uf, EDIM, ODIM, ODIM, EDIM);
    // D4: out = LN(node @ (U+I)), persistent tile loop
    gemm_tile_ln<<<dim3(GRID_MAIN), 512, 0, stream>>>(node, Uf, gamma, beta, out);
}

// Round 8
// 169.506 us; speedup vs baseline: 2.2081x; 2.2081x over previous
//
#include <hip/hip_runtime.h>
#include <hip/hip_bf16.h>

#define NROWS 50000
#define MOBS  2048
#define EDIM  512
#define ODIM  256
#define BM    128
#define NT    391               // ceil(NROWS/BM)

typedef short s16x8 __attribute__((ext_vector_type(8)));
typedef float f32x4 __attribute__((ext_vector_type(4)));

__device__ __forceinline__ unsigned short f32_to_bf16(float f) {
    unsigned int u = __float_as_uint(f);
    u += 0x7fffu + ((u >> 16) & 1u);     // RNE
    return (unsigned short)(u >> 16);
}

__device__ __forceinline__ s16x8 pack_bf16x8(float4 a, float4 b) {
    unsigned int p0, p1, p2, p3;
    asm("v_cvt_pk_bf16_f32 %0, %1, %2" : "=v"(p0) : "v"(a.x), "v"(a.y));
    asm("v_cvt_pk_bf16_f32 %0, %1, %2" : "=v"(p1) : "v"(a.z), "v"(a.w));
    asm("v_cvt_pk_bf16_f32 %0, %1, %2" : "=v"(p2) : "v"(b.x), "v"(b.y));
    asm("v_cvt_pk_bf16_f32 %0, %1, %2" : "=v"(p3) : "v"(b.z), "v"(b.w));
    union { unsigned int u[4]; s16x8 v; } r;
    r.u[0] = p0; r.u[1] = p1; r.u[2] = p2; r.u[3] = p3;
    return r.v;
}

// ---------------------------------------------------------------------------
// Shared 64x64-tile fp32 GEMM body (4x4 micro-tile, 256 thr), plain output.
// TA=0: Aval=A[i*lda+k]  TA=1: Aval=A[k*lda+i]
// TB=0: Bval=B[k*ldb+j]  TB=1: Bval=B[j*ldb+k]
// ---------------------------------------------------------------------------
template <int TA, int TB>
__device__ __forceinline__ void tile64(const float* __restrict__ A,
                                       const float* __restrict__ B,
                                       float* __restrict__ C,
                                       int lda, int ldb, int ldc,
                                       int i0, int j0, int k_lo, int k_hi,
                                       float (*SA)[68], float (*SB)[68]) {
    const int t  = threadIdx.x;
    const int tx = t & 15, ty = t >> 4;

    float acc[4][4];
#pragma unroll
    for (int a = 0; a < 4; ++a)
#pragma unroll
        for (int b = 0; b < 4; ++b) acc[a][b] = 0.f;

    for (int k0 = k_lo; k0 < k_hi; k0 += 16) {
#pragma unroll
        for (int r = 0; r < 4; ++r) {
            int idx = t + 256 * r;
            int mm, kk2;
            if (TA) { mm = idx & 63; kk2 = idx >> 6; }
            else    { kk2 = idx & 15; mm = idx >> 4; }
            SA[kk2][mm] = TA ? A[(size_t)(k0 + kk2) * lda + i0 + mm]
                             : A[(size_t)(i0 + mm) * lda + k0 + kk2];
        }
#pragma unroll
        for (int r = 0; r < 4; ++r) {
            int idx = t + 256 * r;
            int jj, kk2;
            if (TB) { kk2 = idx & 15; jj = idx >> 4; }
            else    { jj = idx & 63; kk2 = idx >> 6; }
            SB[kk2][jj] = TB ? B[(size_t)(j0 + jj) * ldb + k0 + kk2]
                             : B[(size_t)(k0 + kk2) * ldb + j0 + jj];
        }
        __syncthreads();
#pragma unroll
        for (int kk2 = 0; kk2 < 16; ++kk2) {
            float4 a4 = *(const float4*)&SA[kk2][ty * 4];
            float4 b4 = *(const float4*)&SB[kk2][tx * 4];
            float av[4] = {a4.x, a4.y, a4.z, a4.w};
            float bv[4] = {b4.x, b4.y, b4.z, b4.w};
#pragma unroll
            for (int a = 0; a < 4; ++a)
#pragma unroll
                for (int b = 0; b < 4; ++b) acc[a][b] += av[a] * bv[b];
        }
        __syncthreads();
    }
#pragma unroll
    for (int a = 0; a < 4; ++a) {
        float4 o = make_float4(acc[a][0], acc[a][1], acc[a][2], acc[a][3]);
        *(float4*)&C[(size_t)(i0 + ty * 4 + a) * ldc + j0 + tx * 4] = o;
    }
}

// ---------------------------------------------------------------------------
// K1: b<256 -> OV = obs @ Wv^T  [2048,512] K=256 (32x8 tiles)
//     b>=256 -> Pz partials: P = Wq^T @ Wk [512,256], split-K 2 (8x4 tiles x2)
// No atomics, no memset.
// ---------------------------------------------------------------------------
__global__ __launch_bounds__(256) void k1_ovp(const float* __restrict__ obs,
                                              const float* __restrict__ Wq,
                                              const float* __restrict__ Wk,
                                              const float* __restrict__ Wv,
                                              float* __restrict__ OV,
                                              float* __restrict__ Pz) {
    __shared__ float SA[16][68];
    __shared__ float SB[16][68];
    const int b = blockIdx.x;
    if (b < 256) {
        int by = b >> 3, bx = b & 7;
        tile64<0, 1>(obs, Wv, OV, ODIM, ODIM, EDIM,
                     by * 64, bx * 64, 0, ODIM, SA, SB);
    } else {
        int i = b - 256;
        int bx = i & 3, by = (i >> 2) & 7, z = i >> 5;   // z in {0,1}
        tile64<1, 0>(Wq, Wk, Pz + (size_t)z * EDIM * ODIM, EDIM, ODIM, ODIM,
                     by * 64, bx * 64, z * 256, z * 256 + 256, SA, SB);
    }
}

// ---------------------------------------------------------------------------
// K2: GVz partials: GV = obs^T @ OV [256,512], split-K 4 over M=2048.
// grid (8, 4, 4) = 128 blocks.
// ---------------------------------------------------------------------------
__global__ __launch_bounds__(256) void k2_gv(const float* __restrict__ obs,
                                             const float* __restrict__ OV,
                                             float* __restrict__ GVz) {
    __shared__ float SA[16][68];
    __shared__ float SB[16][68];
    const int z = blockIdx.z;
    tile64<1, 0>(obs, OV, GVz + (size_t)z * ODIM * EDIM, ODIM, EDIM, EDIM,
                 blockIdx.y * 64, blockIdx.x * 64, z * 512, z * 512 + 512, SA, SB);
}

// ---------------------------------------------------------------------------
// K3: Uf = frag_bf16( (P0+P1) @ (GV0+..+GV3) + I )  [512,512] K=256.
// grid (8,8). Partials summed during LDS staging.
// ---------------------------------------------------------------------------
__global__ __launch_bounds__(256) void k3_ufrag(const float* __restrict__ Pz,
                                                const float* __restrict__ GVz,
                                                unsigned short* __restrict__ Uf) {
    __shared__ float SA[16][68];
    __shared__ float SB[16][68];
    const int t  = threadIdx.x;
    const int tx = t & 15, ty = t >> 4;
    const int i0 = blockIdx.y * 64, j0 = blockIdx.x * 64;

    float acc[4][4];
#pragma unroll
    for (int a = 0; a < 4; ++a)
#pragma unroll
        for (int b = 0; b < 4; ++b) acc[a][b] = 0.f;

    for (int k0 = 0; k0 < ODIM; k0 += 16) {
#pragma unroll
        for (int r = 0; r < 4; ++r) {
            int idx = t + 256 * r;
            int kk2 = idx & 15, mm = idx >> 4;
            size_t off = (size_t)(i0 + mm) * ODIM + k0 + kk2;
            SA[kk2][mm] = Pz[off] + Pz[off + (size_t)EDIM * ODIM];
        }
#pragma unroll
        for (int r = 0; r < 4; ++r) {
            int idx = t + 256 * r;
            int jj = idx & 63, kk2 = idx >> 6;
            size_t off = (size_t)(k0 + kk2) * EDIM + j0 + jj;
            float v = 0.f;
#pragma unroll
            for (int z = 0; z < 4; ++z) v += GVz[off + (size_t)z * ODIM * EDIM];
            SB[kk2][jj] = v;
        }
        __syncthreads();
#pragma unroll
        for (int kk2 = 0; kk2 < 16; ++kk2) {
            float4 a4 = *(const float4*)&SA[kk2][ty * 4];
            float4 b4 = *(const float4*)&SB[kk2][tx * 4];
            float av[4] = {a4.x, a4.y, a4.z, a4.w};
            float bv[4] = {b4.x, b4.y, b4.z, b4.w};
#pragma unroll
            for (int a = 0; a < 4; ++a)
#pragma unroll
                for (int b = 0; b < 4; ++b) acc[a][b] += av[a] * bv[b];
        }
        __syncthreads();
    }

#pragma unroll
    for (int a = 0; a < 4; ++a)
#pragma unroll
        for (int b = 0; b < 4; ++b) {
            int i = i0 + ty * 4 + a;       // k-dim of main GEMM
            int j = j0 + tx * 4 + b;       // col of main GEMM
            float v = acc[a][b] + (i == j ? 1.f : 0.f);
            int f = j >> 4, lr = j & 15, kk = i >> 5, lk = (i >> 3) & 3;
            Uf[((size_t)((f * 16 + kk) * 64 + lk * 16 + lr)) * 8 + (i & 7)] =
                f32_to_bf16(v);
        }
}

// ---------------------------------------------------------------------------
// Main: out = LayerNorm(node @ (U+I)).  BM=128 tile (halves Uf re-reads).
// 1024 thr = 16 waves; wave (rg=w>>2, c=w&3) owns rows rg*32+[0,32),
// cols c*128+[0,128): acc 2x8 f32x4 = 64 AGPR.
// A: staged per K-half (128 rows x 256 k) as bf16 into 64 KB LDS (XOR-swz);
//    all 8 global loads issued before cvt (MLP). Barrier-free kk loop.
// B: frag-major bf16 Uf from L2, 1 KB coalesced wave loads, 4-frag groups
//    (keeps VGPR <= 128 for 16-wave residency).
// ---------------------------------------------------------------------------
__global__ __launch_bounds__(1024, 4) void gemm128_ln(
    const float* __restrict__ node, const unsigned short* __restrict__ Uf,
    const float* __restrict__ gamma, const float* __restrict__ beta,
    float* __restrict__ out) {
    __shared__ unsigned short Ab[BM * 256];   // 64 KB; aliased for LN stats
    float* lds_s  = (float*)Ab;               // [4][128]
    float* lds_q  = (float*)Ab + 512;         // [4][128]
    float* lds_mu = (float*)Ab + 1024;        // [128]
    float* lds_rs = (float*)Ab + 1152;        // [128]

    const int t  = threadIdx.x;
    const int w  = t >> 6, l = t & 63;
    const int rg = w >> 2, c = w & 3;
    const int lr = l & 15, lk = l >> 4;
    const int m0 = blockIdx.x * BM;

    // stage mapping: thread covers row srow, granules sl, sl+8, sl+16, sl+24
    const int srow = t >> 3;
    const int sl   = t & 7;
    int gr = m0 + srow; if (gr > NROWS - 1) gr = NROWS - 1;
    const float* src = node + (size_t)gr * EDIM;

    f32x4 acc[2][8];
#pragma unroll
    for (int mi = 0; mi < 2; ++mi)
#pragma unroll
        for (int ni = 0; ni < 8; ++ni)
            acc[mi][ni] = (f32x4){0.f, 0.f, 0.f, 0.f};

    // B: wave slice c -> frags f = c*8+ni at granule (f*16+kk)*512 elems
    const unsigned short* ubase = Uf + (size_t)(c * 8) * 16 * 512 + (size_t)l * 8;

    const int arow0 = rg * 32 + lr;           // mi=0 row; (arow&7) == (lr&7)
    const int axor  = (lr & 7) << 4;

#pragma unroll
    for (int half = 0; half < 2; ++half) {
        // ---- stage half: issue all 8 loads, then cvt+write ----
        float4 v[8];
#pragma unroll
        for (int g = 0; g < 4; ++g) {
            const float* p = src + half * 256 + (sl + g * 8) * 8;
            v[2 * g]     = *(const float4*)p;
            v[2 * g + 1] = *(const float4*)(p + 4);
        }
#pragma unroll
        for (int g = 0; g < 4; ++g) {
            s16x8 pk = pack_bf16x8(v[2 * g], v[2 * g + 1]);
            int byte = srow * 512 + (((sl + g * 8) * 16) ^ ((srow & 7) << 4));
            *(s16x8*)((char*)Ab + byte) = pk;
        }
        __syncthreads();

        // ---- 8 kk steps, barrier-free ----
#pragma unroll
        for (int k8 = 0; k8 < 8; ++k8) {
            const int kk = half * 8 + k8;
            const int b0 = arow0 * 512 + ((k8 * 64 + lk * 16) ^ axor);
            s16x8 afr0 = *(const s16x8*)((const char*)Ab + b0);
            s16x8 afr1 = *(const s16x8*)((const char*)Ab + b0 + 16 * 512);

            s16x8 bfr[4];
#pragma unroll
            for (int ni = 0; ni < 4; ++ni)
                bfr[ni] = *(const s16x8*)(ubase + (size_t)ni * 8192 + (size_t)kk * 512);
#pragma unroll
            for (int ni = 0; ni < 4; ++ni) {
                acc[0][ni] = __builtin_amdgcn_mfma_f32_16x16x32_bf16(afr0, bfr[ni], acc[0][ni], 0, 0, 0);
                acc[1][ni] = __builtin_amdgcn_mfma_f32_16x16x32_bf16(afr1, bfr[ni], acc[1][ni], 0, 0, 0);
            }
#pragma unroll
            for (int ni = 0; ni < 4; ++ni)
                bfr[ni] = *(const s16x8*)(ubase + (size_t)(ni + 4) * 8192 + (size_t)kk * 512);
#pragma unroll
            for (int ni = 0; ni < 4; ++ni) {
                acc[0][ni + 4] = __builtin_amdgcn_mfma_f32_16x16x32_bf16(afr0, bfr[ni], acc[0][ni + 4], 0, 0, 0);
                acc[1][ni + 4] = __builtin_amdgcn_mfma_f32_16x16x32_bf16(afr1, bfr[ni], acc[1][ni + 4], 0, 0, 0);
            }
        }
        __syncthreads();   // protect Ab before restage / stats aliasing
    }

    // ---- LN stats (Ab dead; aliased buffers) ----
#pragma unroll
    for (int mi = 0; mi < 2; ++mi) {
#pragma unroll
        for (int j = 0; j < 4; ++j) {
            float sm = 0.f, q = 0.f;
#pragma unroll
            for (int ni = 0; ni < 8; ++ni) {
                float vv = acc[mi][ni][j];
                sm += vv; q += vv * vv;
            }
#pragma unroll
            for (int off = 1; off < 16; off <<= 1) {
                sm += __shfl_xor(sm, off);
                q  += __shfl_xor(q, off);
            }
            if (lr == 0) {
                int row = rg * 32 + mi * 16 + lk * 4 + j;
                lds_s[c * 128 + row] = sm;
                lds_q[c * 128 + row] = q;
            }
        }
    }
    __syncthreads();
    if (t < 128) {
        float sm = lds_s[t] + lds_s[128 + t] + lds_s[256 + t] + lds_s[384 + t];
        float q  = lds_q[t] + lds_q[128 + t] + lds_q[256 + t] + lds_q[384 + t];
        float mu  = sm * (1.f / (float)EDIM);
        float var = q * (1.f / (float)EDIM) - mu * mu;
        lds_mu[t] = mu;
        lds_rs[t] = rsqrtf(var + 1e-6f);
    }
    __syncthreads();

    float gv[8], bv[8];
#pragma unroll
    for (int ni = 0; ni < 8; ++ni) {
        int col = c * 128 + ni * 16 + lr;
        gv[ni] = gamma[col];
        bv[ni] = beta[col];
    }

#pragma unroll
    for (int mi = 0; mi < 2; ++mi) {
#pragma unroll
        for (int j = 0; j < 4; ++j) {
            int row = rg * 32 + mi * 16 + lk * 4 + j;
            int grr = m0 + row;
            if (grr < NROWS) {
                float mu = lds_mu[row], rs = lds_rs[row];
                float* op = out + (size_t)grr * EDIM + c * 128 + lr;
#pragma unroll
                for (int ni = 0; ni < 8; ++ni)
                    op[ni * 16] = (acc[mi][ni][j] - mu) * rs * gv[ni] + bv[ni];
            }
        }
    }
}

// ---------------------------------------------------------------------------
extern "C" void kernel_launch(void* const* d_in, const int* in_sizes, int n_in,
                              void* d_out, int out_size, void* d_ws, size_t ws_size,
                              hipStream_t stream) {
    const float* node  = (const float*)d_in[0];   // [N, E]
    const float* obs   = (const float*)d_in[1];   // [M, O]
    const float* Wq    = (const float*)d_in[2];   // [E, E]
    const float* Wk    = (const float*)d_in[3];   // [E, O]
    const float* Wv    = (const float*)d_in[4];   // [E, O]
    const float* gamma = (const float*)d_in[5];   // [E]
    const float* beta  = (const float*)d_in[6];   // [E]
    float* out = (float*)d_out;

    // ws: OV [2048,512] f32 (4MB) | Pz [2][512,256] f32 (1MB)
    //   | GVz [4][256,512] f32 (2MB) | Uf frag bf16 (512KB)
    float* ws = (float*)d_ws;
    float* OV  = ws;
    float* Pz  = OV  + (size_t)MOBS * EDIM;
    float* GVz = Pz  + 2 * (size_t)EDIM * ODIM;
    unsigned short* Uf = (unsigned short*)(GVz + 4 * (size_t)ODIM * EDIM);

    // K1: OV = obs @ Wv^T  +  Pz = Wq^T @ Wk partials (no memset/atomics)
    k1_ovp<<<dim3(320), 256, 0, stream>>>(obs, Wq, Wk, Wv, OV, Pz);
    // K2: GVz = obs^T @ OV partials (split-K 4)
    k2_gv<<<dim3(8, 4, 4), 256, 0, stream>>>(obs, OV, GVz);
    // K3: Uf = frag(P @ GV + I)
    k3_ufrag<<<dim3(8, 8), 256, 0, stream>>>(Pz, GVz, Uf);
    // Main: out = LN(node @ (U+I)), BM=128
    gemm128_ln<<<dim3(NT), 1024, 0, stream>>>(node, Uf, gamma, beta, out);
}

// Round 9
// 125.407 us; speedup vs baseline: 2.9846x; 1.3516x over previous
//
#include <hip/hip_runtime.h>
#include <hip/hip_bf16.h>

#define NROWS 50000
#define MOBS  2048
#define EDIM  512
#define ODIM  256
#define BM2   128
#define NT2   391               // ceil(50000/128)

typedef short s16x8 __attribute__((ext_vector_type(8)));
typedef float f32x4 __attribute__((ext_vector_type(4)));

typedef const __attribute__((address_space(1))) unsigned int* gptr_t;
typedef __attribute__((address_space(3))) unsigned int* lptr_t;

__device__ __forceinline__ unsigned short f32_to_bf16(float f) {
    unsigned int u = __float_as_uint(f);
    u += 0x7fffu + ((u >> 16) & 1u);     // RNE
    return (unsigned short)(u >> 16);
}

__device__ __forceinline__ s16x8 pack8(f32x4 a, f32x4 b) {
    unsigned int p0, p1, p2, p3;
    asm("v_cvt_pk_bf16_f32 %0, %1, %2" : "=v"(p0) : "v"(a[0]), "v"(a[1]));
    asm("v_cvt_pk_bf16_f32 %0, %1, %2" : "=v"(p1) : "v"(a[2]), "v"(a[3]));
    asm("v_cvt_pk_bf16_f32 %0, %1, %2" : "=v"(p2) : "v"(b[0]), "v"(b[1]));
    asm("v_cvt_pk_bf16_f32 %0, %1, %2" : "=v"(p3) : "v"(b[2]), "v"(b[3]));
    union { unsigned int u[4]; s16x8 v; } r;
    r.u[0] = p0; r.u[1] = p1; r.u[2] = p2; r.u[3] = p3;
    return r.v;
}

// ---------------------------------------------------------------------------
// D1: G = obs^T obs (b<256, split-K 16) and P = Wq^T Wk (b>=256, split-K 4).
// 64x64 tiles, atomicAdd into pre-zeroed C.  (R6 verbatim)
// ---------------------------------------------------------------------------
__global__ __launch_bounds__(256) void gp_fused(const float* __restrict__ obs,
                                                const float* __restrict__ Wq,
                                                const float* __restrict__ Wk,
                                                float* __restrict__ G,
                                                float* __restrict__ P) {
    __shared__ float SA[16][68];
    __shared__ float SB[16][68];
    const int b = blockIdx.x;
    const float *A, *B;
    float* C;
    int lda, ldb, k_lo, k_hi, bx, by;
    if (b < 256) {
        bx = b & 3; by = (b >> 2) & 3; int bz = b >> 4;
        A = obs; B = obs; C = G; lda = ODIM; ldb = ODIM;
        k_lo = bz * (MOBS / 16); k_hi = k_lo + MOBS / 16;
    } else {
        int i = b - 256;
        bx = i & 3; by = (i >> 2) & 7; int bz = i >> 5;
        A = Wq; B = Wk; C = P; lda = EDIM; ldb = ODIM;
        k_lo = bz * (EDIM / 4); k_hi = k_lo + EDIM / 4;
    }
    const int t  = threadIdx.x;
    const int tx = t & 15, ty = t >> 4;
    const int i0 = by * 64, j0 = bx * 64;

    float acc[4][4];
#pragma unroll
    for (int a = 0; a < 4; ++a)
#pragma unroll
        for (int c2 = 0; c2 < 4; ++c2) acc[a][c2] = 0.f;

    for (int k0 = k_lo; k0 < k_hi; k0 += 16) {
#pragma unroll
        for (int r = 0; r < 4; ++r) {
            int idx = t + 256 * r;
            int mm = idx & 63, kk2 = idx >> 6;
            SA[kk2][mm] = A[(size_t)(k0 + kk2) * lda + i0 + mm];
        }
#pragma unroll
        for (int r = 0; r < 4; ++r) {
            int idx = t + 256 * r;
            int jj = idx & 63, kk2 = idx >> 6;
            SB[kk2][jj] = B[(size_t)(k0 + kk2) * ldb + j0 + jj];
        }
        __syncthreads();
#pragma unroll
        for (int kk2 = 0; kk2 < 16; ++kk2) {
            float4 a4 = *(const float4*)&SA[kk2][ty * 4];
            float4 b4 = *(const float4*)&SB[kk2][tx * 4];
            float av[4] = {a4.x, a4.y, a4.z, a4.w};
            float bv[4] = {b4.x, b4.y, b4.z, b4.w};
#pragma unroll
            for (int a = 0; a < 4; ++a)
#pragma unroll
                for (int c2 = 0; c2 < 4; ++c2) acc[a][c2] += av[a] * bv[c2];
        }
        __syncthreads();
    }
#pragma unroll
    for (int a = 0; a < 4; ++a)
#pragma unroll
        for (int c2 = 0; c2 < 4; ++c2)
            atomicAdd(&C[(size_t)(i0 + ty * 4 + a) * ODIM + j0 + tx * 4 + c2],
                      acc[a][c2]);
}

// ---------------------------------------------------------------------------
// Small-chain GEMM (R6 verbatim except FRAG index is now kk-major).
// FRAG layout: granule (kk,f) contiguous 1KB at (kk*32+f)*1024 bytes, so a
// K-step's whole B-tile (32 frag-cols) is one contiguous 32KB chunk for DMA.
// ---------------------------------------------------------------------------
template <int TA, int TB, int SPLIT, int FRAG>
__global__ __launch_bounds__(256) void sgemm4(const float* __restrict__ A,
                                              const float* __restrict__ B,
                                              void* __restrict__ Cv,
                                              int NN, int KK, int lda, int ldb) {
    __shared__ float SA[16][68];
    __shared__ float SB[16][68];
    const int t  = threadIdx.x;
    const int tx = t & 15, ty = t >> 4;
    const int i0 = blockIdx.y * 64, j0 = blockIdx.x * 64;
    int k_lo = 0, k_hi = KK;
    if (SPLIT > 1) { int ch = KK / SPLIT; k_lo = blockIdx.z * ch; k_hi = k_lo + ch; }

    float acc[4][4];
#pragma unroll
    for (int a = 0; a < 4; ++a)
#pragma unroll
        for (int b = 0; b < 4; ++b) acc[a][b] = 0.f;

    for (int k0 = k_lo; k0 < k_hi; k0 += 16) {
#pragma unroll
        for (int r = 0; r < 4; ++r) {
            int idx = t + 256 * r;
            int mm, kk2;
            if (TA) { mm = idx & 63; kk2 = idx >> 6; }
            else    { kk2 = idx & 15; mm = idx >> 4; }
            SA[kk2][mm] = TA ? A[(size_t)(k0 + kk2) * lda + i0 + mm]
                             : A[(size_t)(i0 + mm) * lda + k0 + kk2];
        }
#pragma unroll
        for (int r = 0; r < 4; ++r) {
            int idx = t + 256 * r;
            int jj, kk2;
            if (TB) { kk2 = idx & 15; jj = idx >> 4; }
            else    { jj = idx & 63; kk2 = idx >> 6; }
            SB[kk2][jj] = TB ? B[(size_t)(j0 + jj) * ldb + k0 + kk2]
                             : B[(size_t)(k0 + kk2) * ldb + j0 + jj];
        }
        __syncthreads();
#pragma unroll
        for (int kk2 = 0; kk2 < 16; ++kk2) {
            float4 a4 = *(const float4*)&SA[kk2][ty * 4];
            float4 b4 = *(const float4*)&SB[kk2][tx * 4];
            float av[4] = {a4.x, a4.y, a4.z, a4.w};
            float bv[4] = {b4.x, b4.y, b4.z, b4.w};
#pragma unroll
            for (int a = 0; a < 4; ++a)
#pragma unroll
                for (int b = 0; b < 4; ++b) acc[a][b] += av[a] * bv[b];
        }
        __syncthreads();
    }

    if (FRAG) {
        unsigned short* C = (unsigned short*)Cv;
#pragma unroll
        for (int a = 0; a < 4; ++a)
#pragma unroll
            for (int b = 0; b < 4; ++b) {
                int i = i0 + ty * 4 + a;       // k-dim of main GEMM
                int j = j0 + tx * 4 + b;       // col of main GEMM
                float v = acc[a][b] + (i == j ? 1.f : 0.f);
                size_t idx = ((size_t)(((i >> 5) * 32 + (j >> 4)) * 64
                               + ((i >> 3) & 3) * 16 + (j & 15))) * 8 + (i & 7);
                C[idx] = f32_to_bf16(v);
            }
    } else if (SPLIT > 1) {
        float* C = (float*)Cv;
#pragma unroll
        for (int a = 0; a < 4; ++a)
#pragma unroll
            for (int b = 0; b < 4; ++b)
                atomicAdd(&C[(size_t)(i0 + ty * 4 + a) * NN + j0 + tx * 4 + b],
                          acc[a][b]);
    } else {
        float* C = (float*)Cv;
#pragma unroll
        for (int a = 0; a < 4; ++a) {
            float4 o = make_float4(acc[a][0], acc[a][1], acc[a][2], acc[a][3]);
            *(float4*)&C[(size_t)(i0 + ty * 4 + a) * NN + j0 + tx * 4] = o;
        }
    }
}

// ---------------------------------------------------------------------------
// Main: out = LayerNorm(node @ (U+I)).  m97-structure:
// Tile 128 x 512 (full row -> fused LN), BK=32, 16 K-steps, double-buffered
// LDS (A fp32 16KB + B bf16 32KB per buf = 96KB total), both staged via
// global_load_lds DMA (deep MLP, no VGPR cost). 512 thr = 8 waves, wave
// (rg=w>>2, cg=w&3) owns rows rg*64+[0,64) x cols cg*128+[0,128):
// acc 4x8 f32x4 = 128 regs; launch_bounds(512,2) -> ~256-reg budget.
// A-LDS: [row][8 chunks of 16B], chunk XOR-swizzled by (row&7); the DMA
// *source* is pre-swizzled per-lane (rule: linear dest + inv-swz source).
// ---------------------------------------------------------------------------
__global__ __launch_bounds__(512, 2) void gemm_m97_ln(
    const float* __restrict__ node, const unsigned short* __restrict__ Uf,
    const float* __restrict__ gamma, const float* __restrict__ beta,
    float* __restrict__ out) {
    __shared__ char smem[98304];
    float* Ab = (float*)smem;               // [2][128*32] fp32 (16KB each)
    char*  Bb = smem + 32768;               // [2][32768]  bf16 frag tiles
    float* lds_s  = (float*)smem;           // stats alias (Ab dead after loop)
    float* lds_q  = (float*)smem + 512;
    float* lds_mu = (float*)smem + 1024;
    float* lds_rs = (float*)smem + 1152;

    const int t  = threadIdx.x;
    const int w  = t >> 6, l = t & 63;
    const int rg = w >> 2, cg = w & 3;
    const int lr = l & 15, lk = l >> 4;
    const int m0 = blockIdx.x * BM2;

    // ---- DMA source addresses ----
    // A: lane covers (row = w*8 + (l>>3), chunk = l&7); content must be node
    // granule (chunk ^ (row&7)); row&7 == (l>>3)&7.
    const int sr = w * 8 + (l >> 3);
    const int schunk = (l & 7) ^ ((l >> 3) & 7);
    int gr0 = m0 + sr;      if (gr0 > NROWS - 1) gr0 = NROWS - 1;
    int gr1 = m0 + sr + 64; if (gr1 > NROWS - 1) gr1 = NROWS - 1;
    const char* asrc0 = (const char*)node + (size_t)gr0 * 2048 + schunk * 16;
    const char* asrc1 = (const char*)node + (size_t)gr1 * 2048 + schunk * 16;
    const char* bsrc  = (const char*)Uf + (size_t)w * 4096 + (size_t)l * 16;

    auto dma = [&](int buf, int kt) {
        char* ad = (char*)(Ab + buf * 4096) + w * 1024;     // +l*16 implicit
        __builtin_amdgcn_global_load_lds((gptr_t)(asrc0 + kt * 128),
                                         (lptr_t)ad, 16, 0, 0);
        __builtin_amdgcn_global_load_lds((gptr_t)(asrc1 + kt * 128),
                                         (lptr_t)(ad + 8192), 16, 0, 0);
        char* bd = Bb + buf * 32768 + w * 4096;
        const char* bs = bsrc + (size_t)kt * 32768;
#pragma unroll
        for (int j = 0; j < 4; ++j)
            __builtin_amdgcn_global_load_lds((gptr_t)(bs + j * 1024),
                                             (lptr_t)(bd + j * 1024), 16, 0, 0);
    };

    f32x4 acc[4][8];
#pragma unroll
    for (int mi = 0; mi < 4; ++mi)
#pragma unroll
        for (int ni = 0; ni < 8; ++ni)
            acc[mi][ni] = (f32x4){0.f, 0.f, 0.f, 0.f};

    dma(0, 0);
    __syncthreads();

#pragma unroll 1
    for (int kt = 0; kt < 16; ++kt) {
        if (kt < 15) dma((kt + 1) & 1, kt + 1);

        const int cur = kt & 1;
        const char* bbase = Bb + cur * 32768 + cg * 8192 + l * 16;
        s16x8 bfr[8];
#pragma unroll
        for (int ni = 0; ni < 8; ++ni)
            bfr[ni] = *(const s16x8*)(bbase + ni * 1024);

        s16x8 afr[4];
#pragma unroll
        for (int mi = 0; mi < 4; ++mi) {
            int row = rg * 64 + mi * 16 + lr;          // row&7 == lr&7
            const char* rb = (const char*)(Ab + cur * 4096) + row * 128;
            f32x4 a0 = *(const f32x4*)(rb + ((2 * lk)     ^ (lr & 7)) * 16);
            f32x4 a1 = *(const f32x4*)(rb + ((2 * lk + 1) ^ (lr & 7)) * 16);
            afr[mi] = pack8(a0, a1);
        }
#pragma unroll
        for (int mi = 0; mi < 4; ++mi)
#pragma unroll
            for (int ni = 0; ni < 8; ++ni)
                acc[mi][ni] = __builtin_amdgcn_mfma_f32_16x16x32_bf16(
                    afr[mi], bfr[ni], acc[mi][ni], 0, 0, 0);

        __syncthreads();   // drains DMA for buf kt+1; protects buffer swap
    }

    // ---- LN stats (smem aliased; all K-loop LDS dead) ----
#pragma unroll
    for (int mi = 0; mi < 4; ++mi) {
#pragma unroll
        for (int j = 0; j < 4; ++j) {
            float sm = 0.f, q = 0.f;
#pragma unroll
            for (int ni = 0; ni < 8; ++ni) {
                float v = acc[mi][ni][j];
                sm += v; q += v * v;
            }
#pragma unroll
            for (int off = 1; off < 16; off <<= 1) {
                sm += __shfl_xor(sm, off);
                q  += __shfl_xor(q, off);
            }
            if (lr == 0) {
                int row = rg * 64 + mi * 16 + lk * 4 + j;
                lds_s[cg * 128 + row] = sm;
                lds_q[cg * 128 + row] = q;
            }
        }
    }
    __syncthreads();
    if (t < 128) {
        float sm = lds_s[t] + lds_s[128 + t] + lds_s[256 + t] + lds_s[384 + t];
        float q  = lds_q[t] + lds_q[128 + t] + lds_q[256 + t] + lds_q[384 + t];
        float mu  = sm * (1.f / (float)EDIM);
        float var = q * (1.f / (float)EDIM) - mu * mu;
        lds_mu[t] = mu;
        lds_rs[t] = rsqrtf(var + 1e-6f);
    }
    __syncthreads();

    float gv[8], bv[8];
#pragma unroll
    for (int ni = 0; ni < 8; ++ni) {
        int col = cg * 128 + ni * 16 + lr;
        gv[ni] = gamma[col];
        bv[ni] = beta[col];
    }

#pragma unroll
    for (int mi = 0; mi < 4; ++mi) {
#pragma unroll
        for (int j = 0; j < 4; ++j) {
            int row = rg * 64 + mi * 16 + lk * 4 + j;
            int gr = m0 + row;
            if (gr < NROWS) {
                float mu = lds_mu[row], rs = lds_rs[row];
                float* op = out + (size_t)gr * EDIM + cg * 128 + lr;
#pragma unroll
                for (int ni = 0; ni < 8; ++ni)
                    op[ni * 16] = (acc[mi][ni][j] - mu) * rs * gv[ni] + bv[ni];
            }
        }
    }
}

// ---------------------------------------------------------------------------
extern "C" void kernel_launch(void* const* d_in, const int* in_sizes, int n_in,
                              void* d_out, int out_size, void* d_ws, size_t ws_size,
                              hipStream_t stream) {
    const float* node  = (const float*)d_in[0];   // [N, E]
    const float* obs   = (const float*)d_in[1];   // [M, O]
    const float* Wq    = (const float*)d_in[2];   // [E, E]
    const float* Wk    = (const float*)d_in[3];   // [E, O]
    const float* Wv    = (const float*)d_in[4];   // [E, O]
    const float* gamma = (const float*)d_in[5];   // [E]
    const float* beta  = (const float*)d_in[6];   // [E]
    float* out = (float*)d_out;

    float* ws = (float*)d_ws;
    float*          G  = ws;                        // [256,256] f32
    float*          P  = G  + ODIM * ODIM;          // [512,256] f32 (Wq^T Wk)
    float*          PG = P  + EDIM * ODIM;          // [512,256] f32
    unsigned short* Uf = (unsigned short*)(PG + EDIM * ODIM); // kk-major frag bf16

    // zero split-K accumulators G, P, PG
    hipMemsetAsync((void*)G, 0,
                   (ODIM * ODIM + 2 * EDIM * ODIM) * sizeof(float), stream);

    // D1: G = obs^T obs (split-K 16) + P = Wq^T Wk (split-K 4)
    gp_fused<<<dim3(384), 256, 0, stream>>>(obs, Wq, Wk, G, P);
    // D2: PG = P @ G              [512,256] K=256, split-K 2
    sgemm4<0, 0, 2, 0><<<dim3(4, 8, 2), 256, 0, stream>>>(P, G, PG, ODIM, ODIM, ODIM, ODIM);
    // D3: Uf = frag(PG @ Wv^T + I) [512,512] K=256, kk-major frag bf16
    sgemm4<0, 1, 1, 1><<<dim3(8, 8, 1), 256, 0, stream>>>(PG, Wv, Uf, EDIM, ODIM, ODIM, ODIM);
    // D4: out = LN(node @ (U+I)), m97 DMA structure
    gemm_m97_ln<<<dim3(NT2), 512, 0, stream>>>(node, Uf, gamma, beta, out);
}